// Round 8
// baseline (296.463 us; speedup 1.0000x reference)
//
#include <hip/hip_runtime.h>
#include <stdint.h>

typedef __bf16 bf16x8_t __attribute__((ext_vector_type(8)));
typedef float f32x4_t __attribute__((ext_vector_type(4)));

#define AS1 __attribute__((address_space(1)))
#define AS3 __attribute__((address_space(3)))

static __device__ __forceinline__ unsigned short f2bf(float f) {
  union { float f; unsigned u; } a;
  a.f = f;
  unsigned r = a.u + 0x7fffu + ((a.u >> 16) & 1u);
  return (unsigned short)(r >> 16);
}

static __device__ __forceinline__ unsigned pack2bf(float lo, float hi) {
  return (unsigned)f2bf(lo) | ((unsigned)f2bf(hi) << 16);
}

// ---------- 0. zero fill (for atomic split-K accumulators) ----------
__global__ void zero_f32(float* __restrict__ p, long n4) {
  long i = (long)blockIdx.x * blockDim.x + threadIdx.x;
  if (i < n4) *(float4*)(p + i * 4) = make_float4(0.f, 0.f, 0.f, 0.f);
}

// ---------- 1. fp32 -> bf16 elementwise ----------
__global__ void cvt_bf16_kernel(const float* __restrict__ in, unsigned short* __restrict__ out) {
  long i = ((long)blockIdx.x * blockDim.x + threadIdx.x) * 4;
  float4 v = *(const float4*)(in + i);
  ushort4 o;
  o.x = f2bf(v.x);
  o.y = f2bf(v.y);
  o.z = f2bf(v.z);
  o.w = f2bf(v.w);
  *(ushort4*)(out + i) = o;
}

// ---------- 2. fp32 [R][C] (row stride ld) -> bf16 [C][R] (row stride dld) ----------
__global__ void transpose_f32_bf16(const float* __restrict__ src, unsigned short* __restrict__ dst,
                                   int ld, int dld, long sbs, long dbs) {
  __shared__ float tile[64][65];
  src += (long)blockIdx.z * sbs;
  dst += (long)blockIdx.z * dbs;
  const int c0 = blockIdx.x * 64, r0 = blockIdx.y * 64;
  const int tx = threadIdx.x, ty = threadIdx.y;
#pragma unroll
  for (int j = 0; j < 64; j += 4)
    tile[ty + j][tx] = src[(long)(r0 + ty + j) * ld + (c0 + tx)];
  __syncthreads();
#pragma unroll
  for (int j = 0; j < 64; j += 4)
    dst[(long)(c0 + ty + j) * dld + (r0 + tx)] = f2bf(tile[tx][ty + j]);
}

// ---------- 3. GEMM split-K=2: C[M][N] += A[M][K-half] * Bt[N][K-half]^T ----------
// 1D grid nx*ny*2 (nwg%8==0), bijective XCD-chunk swizzle, z = K-slice.
// Epilogue: fp32 atomicAdd into zero-initialized C (2 commutative addends ->
// bitwise deterministic). 4-4.5 blocks/CU residency (was 2 -> ~470 TF; m102
// scaling says 4/CU -> ~830 TF).
__global__ __launch_bounds__(256) void gemm_bt_sk(const unsigned short* __restrict__ A,
                                                  const unsigned short* __restrict__ Bt,
                                                  float* __restrict__ C,
                                                  int M, int N, int K, int nx, int ny) {
  __shared__ unsigned short As[128 * 32];
  __shared__ unsigned short Bs[128 * 32];
  const int nwg = nx * ny * 2;
  const int bid = blockIdx.x;
  const int swz = (bid & 7) * (nwg >> 3) + (bid >> 3);  // XCD chunking (nwg%8==0)
  const int per = nx * ny;
  const int bz = swz / per;
  const int rem = swz - bz * per;
  const int by = rem / nx;
  const int bx = rem - by * nx;
  const int Kh = K >> 1;
  const int k0 = bz * Kh;

  const int tid = threadIdx.x;
  const int wid = tid >> 6, lane = tid & 63;
  const int r16 = lane & 15, g = lane >> 4;
  const long bm = (long)by * 128;
  const long bn = (long)bx * 128;
  const int wr = (wid >> 1) * 64, wc = (wid & 1) * 64;
  f32x4_t acc[4][4];
#pragma unroll
  for (int i = 0; i < 4; i++)
#pragma unroll
    for (int j = 0; j < 4; j++) acc[i][j] = (f32x4_t){0.f, 0.f, 0.f, 0.f};

  for (int kt = k0; kt < k0 + Kh; kt += 32) {
#pragma unroll
    for (int i = 0; i < 2; i++) {
      const int chunk = (i * 4 + wid) * 64 + lane;
      const int row = chunk >> 2, col = (chunk & 3) * 8;
      __builtin_amdgcn_global_load_lds(
          (const AS1 void*)(A + (bm + row) * K + kt + col),
          (AS3 void*)(As + chunk * 8), 16, 0, 0);
      __builtin_amdgcn_global_load_lds(
          (const AS1 void*)(Bt + (bn + row) * K + kt + col),
          (AS3 void*)(Bs + chunk * 8), 16, 0, 0);
    }
    __syncthreads();
    bf16x8_t af[4], bfr[4];
#pragma unroll
    for (int mi = 0; mi < 4; mi++)
      af[mi] = *(const bf16x8_t*)(As + (wr + mi * 16 + r16) * 32 + g * 8);
#pragma unroll
    for (int ni = 0; ni < 4; ni++)
      bfr[ni] = *(const bf16x8_t*)(Bs + (wc + ni * 16 + r16) * 32 + g * 8);
#pragma unroll
    for (int mi = 0; mi < 4; mi++)
#pragma unroll
      for (int ni = 0; ni < 4; ni++)
        acc[mi][ni] = __builtin_amdgcn_mfma_f32_16x16x32_bf16(af[mi], bfr[ni], acc[mi][ni], 0, 0, 0);
    __syncthreads();
  }
#pragma unroll
  for (int mi = 0; mi < 4; mi++)
#pragma unroll
    for (int ni = 0; ni < 4; ni++) {
      const long rowb = bm + wr + mi * 16 + 4 * g;
      const long colb = bn + wc + ni * 16 + r16;
#pragma unroll
      for (int j = 0; j < 4; j++)
        atomicAdd(&C[(rowb + j) * N + colb], acc[mi][ni][j]);
    }
}

// ---------- 4. RoPE + scale fold + layout ----------
__global__ void rope_kernel(const float* __restrict__ qkv,
                            const float* __restrict__ sinp,
                            const float* __restrict__ cosp,
                            unsigned short* __restrict__ qr,
                            unsigned short* __restrict__ kr) {
  const int row = blockIdx.x;  // b*2048 + t
  const int b = row >> 11, t = row & 2047;
  const float* src = qkv + (long)row * 2304;
  const int tid = threadIdx.x;
  const int d = tid & 127;
  const int dp = (d + 64) & 127;
  const float c = cosp[t * 128 + d];
  const float s = sinp[t * 128 + d];
  const float sgn = (d < 64) ? -1.f : 1.f;
  for (int h = (tid >> 7); h < 16; h += 2) {
    const float x0 = src[h * 128 + d];
    const float xp = src[h * 128 + dp];
    qr[((long)((b * 16 + h) * 2048 + t)) * 128 + d] = f2bf((x0 * c + sgn * xp * s) * 0.0078125f);
  }
  if (tid < 128) {
    const float x0 = src[2048 + d];
    const float xp = src[2048 + dp];
    kr[((long)(b * 2048 + t)) * 128 + d] = f2bf(x0 * c + sgn * xp * s);
  }
}

// ---------- 5. causal MQA flash attention (v7, unchanged from round 7) ----------
__global__ __launch_bounds__(256, 2)
void mqa_attn(const unsigned short* __restrict__ qr,
              const unsigned short* __restrict__ kr,
              const unsigned short* __restrict__ vT,
              unsigned short* __restrict__ ao) {
  __shared__ unsigned short Kb[2][64 * 128];   // 2 x 16KB K tiles
  __shared__ unsigned short Vb[128 * 64];      // 16KB V^T tile (single buffer)
  __shared__ unsigned short plds[4][16 * 64];  // per-wave P tile (2KB each)
  const int idx = blockIdx.x;  // 512 blocks
  const int pj = idx & 15, h = (idx >> 4) & 15, b = idx >> 8;
  const int tid = threadIdx.x;
  const int wid = tid >> 6, lane = tid & 63;
  const int r = lane & 15, g = lane >> 4;
  const int rs = r & 7;
  char* pw = (char*)&plds[wid][0];

  const unsigned short* kbase = kr + (long)b * 2048 * 128;
  const unsigned short* vbase = vT + (long)b * 128 * 2048;
  const unsigned short* qh = qr + (long)(b * 16 + h) * 2048 * 128;

  const int scol = (tid & 15) ^ ((tid >> 4) & 7);  // K staging src granule
  const int vscol = (tid & 7) ^ ((tid >> 3) & 7);  // V staging src granule

  f32x4_t o[8];
#pragma unroll
  for (int i = 0; i < 8; i++) o[i] = (f32x4_t){0.f, 0.f, 0.f, 0.f};
  float m = 0.f, lsum = 0.f;

  int tile = pj;
  bf16x8_t qf[4];
  {
    const unsigned short* qp = qh + (long)(tile * 64 + wid * 16 + r) * 128 + g * 8;
#pragma unroll
    for (int c = 0; c < 4; c++) qf[c] = *(const bf16x8_t*)(qp + c * 32);
  }

  // prologue: stage K block 0 into Kb[0]
#pragma unroll
  for (int i = 0; i < 4; i++) {
    const int row = i * 16 + (tid >> 4);
    __builtin_amdgcn_global_load_lds(
        (const AS1 void*)(kbase + (long)row * 128 + scol * 8),
        (AS3 void*)(&Kb[0][(i * 256 + tid) * 8]), 16, 0, 0);
  }
  asm volatile("s_waitcnt vmcnt(0)" ::: "memory");
  __builtin_amdgcn_s_barrier();

  const int switch_s = pj + 1;
  for (int s = 0; s <= 32; s++) {
    const int cur = s & 1;
    const int kv0 = (s <= pj) ? 64 * s : 64 * (s - 1 - pj);

    // 0. tile switch: flush tile A (O stores + Q reload) before staging issue
    if (s == switch_s) {
      float lt = lsum;
      lt += __shfl_xor(lt, 16);
      lt += __shfl_xor(lt, 32);
      float rl[4];
#pragma unroll
      for (int jj = 0; jj < 4; jj++) rl[jj] = 1.0f / __shfl(lt, 4 * g + jj);
      unsigned short* aop = ao + ((long)(b * 2048 + tile * 64 + wid * 16 + 4 * g)) * 2048 + h * 128 + r;
#pragma unroll
      for (int dt = 0; dt < 8; dt++)
#pragma unroll
        for (int jj = 0; jj < 4; jj++)
          aop[(long)jj * 2048 + dt * 16] = f2bf(o[dt][jj] * rl[jj]);
      tile = 31 - pj;
      const unsigned short* qp = qh + (long)(tile * 64 + wid * 16 + r) * 128 + g * 8;
#pragma unroll
      for (int c = 0; c < 4; c++) qf[c] = *(const bf16x8_t*)(qp + c * 32);
#pragma unroll
      for (int i = 0; i < 8; i++) o[i] = (f32x4_t){0.f, 0.f, 0.f, 0.f};
      m = 0.f;
      lsum = 0.f;
    }

    // 1. V(s) staging: V^T[0..127][kv0..kv0+63] -> Vb (granule-swizzled)
#pragma unroll
    for (int i = 0; i < 4; i++) {
      const int vrow = i * 32 + (tid >> 3);
      __builtin_amdgcn_global_load_lds(
          (const AS1 void*)(vbase + (long)vrow * 2048 + kv0 + vscol * 8),
          (AS3 void*)(&Vb[(i * 256 + tid) * 8]), 16, 0, 0);
    }
    // 2. K(s+1) staging into the other K buffer
    if (s < 32) {
      const int kvn = (s + 1 <= pj) ? 64 * (s + 1) : 64 * (s - pj);
#pragma unroll
      for (int i = 0; i < 4; i++) {
        const int row = i * 16 + (tid >> 4);
        __builtin_amdgcn_global_load_lds(
            (const AS1 void*)(kbase + (long)(kvn + row) * 128 + scol * 8),
            (AS3 void*)(&Kb[cur ^ 1][(i * 256 + tid) * 8]), 16, 0, 0);
      }
    }
    __builtin_amdgcn_sched_barrier(0);

    // 3. QK^T from LDS K tile
    f32x4_t sc[4];
#pragma unroll
    for (int t = 0; t < 4; t++) sc[t] = (f32x4_t){0.f, 0.f, 0.f, 0.f};
    const unsigned short* Kcur = &Kb[cur][0];
    __builtin_amdgcn_s_setprio(1);
#pragma unroll
    for (int t = 0; t < 4; t++) {
      const unsigned short* krow = Kcur + (16 * t + r) * 128;
#pragma unroll
      for (int c = 0; c < 4; c++) {
        const bf16x8_t kf = *(const bf16x8_t*)(krow + (((4 * c + g) ^ rs) << 3));
        sc[t] = __builtin_amdgcn_mfma_f32_16x16x32_bf16(kf, qf[c], sc[t], 0, 0, 0);
      }
    }
    __builtin_amdgcn_s_setprio(0);

    // 4. causal mask on the current tile's last stage
    if (s == pj || s == 32) {
#pragma unroll
      for (int t = 0; t < 4; t++)
#pragma unroll
        for (int jj = 0; jj < 4; jj++)
          if (t * 16 + 4 * g + jj > wid * 16 + r) sc[t][jj] = -1e30f;
    }
    // 5. softmax (defer-max fast path)
    float lm = sc[0][0];
#pragma unroll
    for (int t = 0; t < 4; t++)
#pragma unroll
      for (int jj = 0; jj < 4; jj++) lm = fmaxf(lm, sc[t][jj]);
    if (!__all(lm <= m + 8.f)) {  // rare rescale path
      float pm = lm;
      pm = fmaxf(pm, __shfl_xor(pm, 16));
      pm = fmaxf(pm, __shfl_xor(pm, 32));
      const float mnew = fmaxf(m, pm);
      const float alpha = __expf(m - mnew);
      lsum *= alpha;
      float aj[4];
#pragma unroll
      for (int jj = 0; jj < 4; jj++) aj[jj] = __shfl(alpha, 4 * g + jj);
#pragma unroll
      for (int dt = 0; dt < 8; dt++) {
        o[dt][0] *= aj[0]; o[dt][1] *= aj[1]; o[dt][2] *= aj[2]; o[dt][3] *= aj[3];
      }
      m = mnew;
    }
    float p[16];
#pragma unroll
    for (int t = 0; t < 4; t++)
#pragma unroll
      for (int jj = 0; jj < 4; jj++) p[4 * t + jj] = __expf(sc[t][jj] - m);
    float ls = 0.f;
#pragma unroll
    for (int i = 0; i < 16; i++) ls += p[i];
    lsum += ls;

    // 6. P redistribute through per-wave LDS tile
    asm volatile("" ::: "memory");
#pragma unroll
    for (int t = 0; t < 4; t++) {
      uint2 w = {pack2bf(p[4 * t], p[4 * t + 1]), pack2bf(p[4 * t + 2], p[4 * t + 3])};
      *(uint2*)(pw + r * 128 + (((2 * t + (g >> 1)) ^ rs) << 4) + ((g & 1) << 3)) = w;
    }
    asm volatile("s_waitcnt lgkmcnt(0)" ::: "memory");
    const bf16x8_t pa0 = *(const bf16x8_t*)(pw + r * 128 + ((g ^ rs) << 4));
    const bf16x8_t pa1 = *(const bf16x8_t*)(pw + r * 128 + (((4 + g) ^ rs) << 4));

    // 7. V visibility: own V-DMAs done (K-next still in flight), then barrier
    if (s < 32)
      asm volatile("s_waitcnt vmcnt(4)" ::: "memory");
    else
      asm volatile("s_waitcnt vmcnt(0)" ::: "memory");
    __builtin_amdgcn_s_barrier();

    // 8. PV from LDS V tile (swizzled ds_read_b128)
    __builtin_amdgcn_s_setprio(1);
#pragma unroll
    for (int dt = 0; dt < 8; dt++) {
      const bf16x8_t vfA = *(const bf16x8_t*)(Vb + (dt * 16 + r) * 64 + ((g ^ rs) << 3));
      o[dt] = __builtin_amdgcn_mfma_f32_16x16x32_bf16(pa0, vfA, o[dt], 0, 0, 0);
    }
#pragma unroll
    for (int dt = 0; dt < 8; dt++) {
      const bf16x8_t vfB = *(const bf16x8_t*)(Vb + (dt * 16 + r) * 64 + (((4 + g) ^ rs) << 3));
      o[dt] = __builtin_amdgcn_mfma_f32_16x16x32_bf16(pa1, vfB, o[dt], 0, 0, 0);
    }
    __builtin_amdgcn_s_setprio(0);

    // 9. drain K(s+1) staging + sync (protects Vb/Kb for next stage)
    asm volatile("s_waitcnt vmcnt(0)" ::: "memory");
    __builtin_amdgcn_s_barrier();
  }
  // epilogue: flush tile B
  {
    float lt = lsum;
    lt += __shfl_xor(lt, 16);
    lt += __shfl_xor(lt, 32);
    float rl[4];
#pragma unroll
    for (int jj = 0; jj < 4; jj++) rl[jj] = 1.0f / __shfl(lt, 4 * g + jj);
    unsigned short* aop = ao + ((long)(b * 2048 + tile * 64 + wid * 16 + 4 * g)) * 2048 + h * 128 + r;
#pragma unroll
    for (int dt = 0; dt < 8; dt++)
#pragma unroll
      for (int jj = 0; jj < 4; jj++)
        aop[(long)jj * 2048 + dt * 16] = f2bf(o[dt][jj] * rl[jj]);
  }
}

extern "C" void kernel_launch(void* const* d_in, const int* in_sizes, int n_in,
                              void* d_out, int out_size, void* d_ws, size_t ws_size,
                              hipStream_t stream) {
  const float* x    = (const float*)d_in[0];
  const float* sinp = (const float*)d_in[1];
  const float* cosp = (const float*)d_in[2];
  const float* Wqkv = (const float*)d_in[3];
  const float* Wo   = (const float*)d_in[4];
  float* out = (float*)d_out;
  char* ws = (char*)d_ws;

  const int B = 2, T = 2048, D = 2048, H = 16, HD = 128;
  const int M = B * T;        // 4096
  const int NQ = D + 2 * HD;  // 2304

  unsigned short* xb    = (unsigned short*)(ws + 0);         // 16,777,216
  unsigned short* wqkvT = (unsigned short*)(ws + 16777216);  //  9,437,184
  unsigned short* woT   = (unsigned short*)(ws + 26214400);  //  8,388,608
  float*          qkv   = (float*)         (ws + 34603008);  // 37,748,736
  unsigned short* qr    = (unsigned short*)(ws + 72351744);  // 16,777,216
  unsigned short* kr    = (unsigned short*)(ws + 89128960);  //  1,048,576
  unsigned short* vT    = (unsigned short*)(ws + 90177536);  //  1,048,576
  unsigned short* ao    = xb;  // reuse xb after first GEMM

  const long nqkv = (long)M * NQ;  // 9,437,184 (div by 4)
  const long nout = (long)M * D;   // 8,388,608 (div by 4)

  dim3 tb(64, 4);
  // zero split-K accumulators (must precede their GEMMs; stream-ordered)
  zero_f32<<<(int)(nqkv / 4 + 255) / 256, 256, 0, stream>>>(qkv, nqkv / 4);
  zero_f32<<<(int)(nout / 4 + 255) / 256, 256, 0, stream>>>(out, nout / 4);
  cvt_bf16_kernel<<<(M * D) / 1024, 256, 0, stream>>>(x, xb);
  transpose_f32_bf16<<<dim3(NQ / 64, D / 64, 1), tb, 0, stream>>>(Wqkv, wqkvT, NQ, D, 0, 0);
  transpose_f32_bf16<<<dim3(D / 64, D / 64, 1), tb, 0, stream>>>(Wo, woT, D, D, 0, 0);
  // qkv += x @ Wqkv  (split-K=2, atomic)
  gemm_bt_sk<<<dim3((NQ / 128) * (M / 128) * 2), 256, 0, stream>>>(xb, wqkvT, qkv, M, NQ, D, NQ / 128, M / 128);
  rope_kernel<<<M, 256, 0, stream>>>(qkv, sinp, cosp, qr, kr);
  transpose_f32_bf16<<<dim3(HD / 64, T / 64, B), tb, 0, stream>>>(
      qkv + 2176, vT, NQ, T, (long)T * NQ, (long)HD * T);
  mqa_attn<<<dim3(512), 256, 0, stream>>>(qr, kr, vT, ao);
  // out += ao @ Wo  (split-K=2, atomic)
  gemm_bt_sk<<<dim3((D / 128) * (M / 128) * 2), 256, 0, stream>>>(ao, woT, out, M, D, D, D / 128, M / 128);
}

// Round 9
// 203.009 us; speedup vs baseline: 1.4603x; 1.4603x over previous
//
#include <hip/hip_runtime.h>
#include <stdint.h>

typedef __bf16 bf16x8_t __attribute__((ext_vector_type(8)));
typedef float f32x4_t __attribute__((ext_vector_type(4)));

#define AS1 __attribute__((address_space(1)))
#define AS3 __attribute__((address_space(3)))

static __device__ __forceinline__ unsigned short f2bf(float f) {
  union { float f; unsigned u; } a;
  a.f = f;
  unsigned r = a.u + 0x7fffu + ((a.u >> 16) & 1u);
  return (unsigned short)(r >> 16);
}

static __device__ __forceinline__ unsigned pack2bf(float lo, float hi) {
  return (unsigned)f2bf(lo) | ((unsigned)f2bf(hi) << 16);
}

// ---------- 1. fp32 -> bf16 elementwise ----------
__global__ void cvt_bf16_kernel(const float* __restrict__ in, unsigned short* __restrict__ out) {
  long i = ((long)blockIdx.x * blockDim.x + threadIdx.x) * 4;
  float4 v = *(const float4*)(in + i);
  ushort4 o;
  o.x = f2bf(v.x);
  o.y = f2bf(v.y);
  o.z = f2bf(v.z);
  o.w = f2bf(v.w);
  *(ushort4*)(out + i) = o;
}

// ---------- 2. fp32 [R][C] (row stride ld) -> bf16 [C][R] (row stride dld) ----------
__global__ void transpose_f32_bf16(const float* __restrict__ src, unsigned short* __restrict__ dst,
                                   int ld, int dld, long sbs, long dbs) {
  __shared__ float tile[64][65];
  src += (long)blockIdx.z * sbs;
  dst += (long)blockIdx.z * dbs;
  const int c0 = blockIdx.x * 64, r0 = blockIdx.y * 64;
  const int tx = threadIdx.x, ty = threadIdx.y;
#pragma unroll
  for (int j = 0; j < 64; j += 4)
    tile[ty + j][tx] = src[(long)(r0 + ty + j) * ld + (c0 + tx)];
  __syncthreads();
#pragma unroll
  for (int j = 0; j < 64; j += 4)
    dst[(long)(c0 + ty + j) * dld + (r0 + tx)] = f2bf(tile[tx][ty + j]);
}

// ---------- 3. GEMM: C[M][N] = A[M][K] * Bt[N][K]^T  (bf16 in, fp32 out) ----------
// m97 fragment math, NEW pipeline: triple-buffered LDS (48KB), counted vmcnt(4)
// (never 0 in steady state) + raw s_barrier -> no per-iter DMA drain.
// Slot swizzle (slot ^= R&3, both sides) cuts ds_read conflicts 8-way -> 4-way.
// Bijective XCD chunk swizzle (grid % 8 == 0).
__global__ __launch_bounds__(256) void gemm_bt(const unsigned short* __restrict__ A,
                                               const unsigned short* __restrict__ Bt,
                                               float* __restrict__ C,
                                               int M, int N, int K, int nx) {
  __shared__ unsigned short As[3][128 * 32];
  __shared__ unsigned short Bs[3][128 * 32];
  const int nwg = gridDim.x;
  const int bid = blockIdx.x;
  const int swz = (bid & 7) * (nwg >> 3) + (bid >> 3);  // XCD chunking
  const int by = swz / nx;
  const int bx = swz - by * nx;

  const int tid = threadIdx.x;
  const int wid = tid >> 6, lane = tid & 63;
  const int r16 = lane & 15, g = lane >> 4;
  const long bm = (long)by * 128;
  const long bn = (long)bx * 128;
  const int wr = (wid >> 1) * 64, wc = (wid & 1) * 64;
  const int gr = g ^ (r16 & 3);  // swizzled read granule (R&3 == r16&3 for our rows)
  // staging coords: chunk = (i*4+wid)*64+lane; R=chunk>>2; slot=chunk&3
  const int sslot = (lane & 3) ^ ((lane >> 2) & 3);  // source granule = slot ^ (R&3)

  f32x4_t acc[4][4];
#pragma unroll
  for (int i = 0; i < 4; i++)
#pragma unroll
    for (int j = 0; j < 4; j++) acc[i][j] = (f32x4_t){0.f, 0.f, 0.f, 0.f};

  const int NT = K >> 5;

#define STAGE_G(buf, kt)                                                              \
  {                                                                                   \
    _Pragma("unroll") for (int i = 0; i < 2; i++) {                                   \
      const int chunk = (i * 4 + wid) * 64 + lane;                                    \
      const int row = chunk >> 2;                                                     \
      __builtin_amdgcn_global_load_lds(                                               \
          (const AS1 void*)(A + (bm + row) * K + (kt) + sslot * 8),                   \
          (AS3 void*)(&As[buf][chunk * 8]), 16, 0, 0);                                \
      __builtin_amdgcn_global_load_lds(                                               \
          (const AS1 void*)(Bt + (bn + row) * K + (kt) + sslot * 8),                  \
          (AS3 void*)(&Bs[buf][chunk * 8]), 16, 0, 0);                                \
    }                                                                                 \
  }

  // prologue: KT0 -> buf0, KT1 -> buf1; wait KT0 landed (KT1 in flight)
  STAGE_G(0, 0)
  STAGE_G(1, 32)
  asm volatile("s_waitcnt vmcnt(4)" ::: "memory");
  __builtin_amdgcn_s_barrier();

  for (int T = 0; T < NT; T++) {
    const int cur = T % 3;
    if (T + 2 < NT) {
      const int nb = (T + 2) % 3;
      STAGE_G(nb, (T + 2) * 32)
    }
    __builtin_amdgcn_sched_barrier(0);
    bf16x8_t af[4], bfr[4];
#pragma unroll
    for (int mi = 0; mi < 4; mi++)
      af[mi] = *(const bf16x8_t*)(&As[cur][(wr + mi * 16 + r16) * 32 + gr * 8]);
#pragma unroll
    for (int ni = 0; ni < 4; ni++)
      bfr[ni] = *(const bf16x8_t*)(&Bs[cur][(wc + ni * 16 + r16) * 32 + gr * 8]);
    __builtin_amdgcn_s_setprio(1);
#pragma unroll
    for (int mi = 0; mi < 4; mi++)
#pragma unroll
      for (int ni = 0; ni < 4; ni++)
        acc[mi][ni] = __builtin_amdgcn_mfma_f32_16x16x32_bf16(af[mi], bfr[ni], acc[mi][ni], 0, 0, 0);
    __builtin_amdgcn_s_setprio(0);
    // KT(T+1) guaranteed landed: older than the 4 stage-instrs just issued
    if (T + 2 < NT)
      asm volatile("s_waitcnt vmcnt(4)" ::: "memory");
    else
      asm volatile("s_waitcnt vmcnt(0)" ::: "memory");
    __builtin_amdgcn_s_barrier();
  }
#undef STAGE_G

#pragma unroll
  for (int mi = 0; mi < 4; mi++)
#pragma unroll
    for (int ni = 0; ni < 4; ni++) {
      const long rowb = bm + wr + mi * 16 + 4 * g;
      const long colb = bn + wc + ni * 16 + r16;
#pragma unroll
      for (int j = 0; j < 4; j++)
        C[(rowb + j) * N + colb] = acc[mi][ni][j];
    }
}

// ---------- 4. RoPE + scale fold + layout ----------
__global__ void rope_kernel(const float* __restrict__ qkv,
                            const float* __restrict__ sinp,
                            const float* __restrict__ cosp,
                            unsigned short* __restrict__ qr,
                            unsigned short* __restrict__ kr) {
  const int row = blockIdx.x;  // b*2048 + t
  const int b = row >> 11, t = row & 2047;
  const float* src = qkv + (long)row * 2304;
  const int tid = threadIdx.x;
  const int d = tid & 127;
  const int dp = (d + 64) & 127;
  const float c = cosp[t * 128 + d];
  const float s = sinp[t * 128 + d];
  const float sgn = (d < 64) ? -1.f : 1.f;
  for (int h = (tid >> 7); h < 16; h += 2) {
    const float x0 = src[h * 128 + d];
    const float xp = src[h * 128 + dp];
    qr[((long)((b * 16 + h) * 2048 + t)) * 128 + d] = f2bf((x0 * c + sgn * xp * s) * 0.0078125f);
  }
  if (tid < 128) {
    const float x0 = src[2048 + d];
    const float xp = src[2048 + dp];
    kr[((long)(b * 2048 + t)) * 128 + d] = f2bf(x0 * c + sgn * xp * s);
  }
}

// ---------- 5. causal MQA flash attention (v7, unchanged) ----------
__global__ __launch_bounds__(256, 2)
void mqa_attn(const unsigned short* __restrict__ qr,
              const unsigned short* __restrict__ kr,
              const unsigned short* __restrict__ vT,
              unsigned short* __restrict__ ao) {
  __shared__ unsigned short Kb[2][64 * 128];   // 2 x 16KB K tiles
  __shared__ unsigned short Vb[128 * 64];      // 16KB V^T tile (single buffer)
  __shared__ unsigned short plds[4][16 * 64];  // per-wave P tile (2KB each)
  const int idx = blockIdx.x;  // 512 blocks
  const int pj = idx & 15, h = (idx >> 4) & 15, b = idx >> 8;
  const int tid = threadIdx.x;
  const int wid = tid >> 6, lane = tid & 63;
  const int r = lane & 15, g = lane >> 4;
  const int rs = r & 7;
  char* pw = (char*)&plds[wid][0];

  const unsigned short* kbase = kr + (long)b * 2048 * 128;
  const unsigned short* vbase = vT + (long)b * 128 * 2048;
  const unsigned short* qh = qr + (long)(b * 16 + h) * 2048 * 128;

  const int scol = (tid & 15) ^ ((tid >> 4) & 7);  // K staging src granule
  const int vscol = (tid & 7) ^ ((tid >> 3) & 7);  // V staging src granule

  f32x4_t o[8];
#pragma unroll
  for (int i = 0; i < 8; i++) o[i] = (f32x4_t){0.f, 0.f, 0.f, 0.f};
  float m = 0.f, lsum = 0.f;

  int tile = pj;
  bf16x8_t qf[4];
  {
    const unsigned short* qp = qh + (long)(tile * 64 + wid * 16 + r) * 128 + g * 8;
#pragma unroll
    for (int c = 0; c < 4; c++) qf[c] = *(const bf16x8_t*)(qp + c * 32);
  }

  // prologue: stage K block 0 into Kb[0]
#pragma unroll
  for (int i = 0; i < 4; i++) {
    const int row = i * 16 + (tid >> 4);
    __builtin_amdgcn_global_load_lds(
        (const AS1 void*)(kbase + (long)row * 128 + scol * 8),
        (AS3 void*)(&Kb[0][(i * 256 + tid) * 8]), 16, 0, 0);
  }
  asm volatile("s_waitcnt vmcnt(0)" ::: "memory");
  __builtin_amdgcn_s_barrier();

  const int switch_s = pj + 1;
  for (int s = 0; s <= 32; s++) {
    const int cur = s & 1;
    const int kv0 = (s <= pj) ? 64 * s : 64 * (s - 1 - pj);

    // 0. tile switch: flush tile A (O stores + Q reload) before staging issue
    if (s == switch_s) {
      float lt = lsum;
      lt += __shfl_xor(lt, 16);
      lt += __shfl_xor(lt, 32);
      float rl[4];
#pragma unroll
      for (int jj = 0; jj < 4; jj++) rl[jj] = 1.0f / __shfl(lt, 4 * g + jj);
      unsigned short* aop = ao + ((long)(b * 2048 + tile * 64 + wid * 16 + 4 * g)) * 2048 + h * 128 + r;
#pragma unroll
      for (int dt = 0; dt < 8; dt++)
#pragma unroll
        for (int jj = 0; jj < 4; jj++)
          aop[(long)jj * 2048 + dt * 16] = f2bf(o[dt][jj] * rl[jj]);
      tile = 31 - pj;
      const unsigned short* qp = qh + (long)(tile * 64 + wid * 16 + r) * 128 + g * 8;
#pragma unroll
      for (int c = 0; c < 4; c++) qf[c] = *(const bf16x8_t*)(qp + c * 32);
#pragma unroll
      for (int i = 0; i < 8; i++) o[i] = (f32x4_t){0.f, 0.f, 0.f, 0.f};
      m = 0.f;
      lsum = 0.f;
    }

    // 1. V(s) staging: V^T[0..127][kv0..kv0+63] -> Vb (granule-swizzled)
#pragma unroll
    for (int i = 0; i < 4; i++) {
      const int vrow = i * 32 + (tid >> 3);
      __builtin_amdgcn_global_load_lds(
          (const AS1 void*)(vbase + (long)vrow * 2048 + kv0 + vscol * 8),
          (AS3 void*)(&Vb[(i * 256 + tid) * 8]), 16, 0, 0);
    }
    // 2. K(s+1) staging into the other K buffer
    if (s < 32) {
      const int kvn = (s + 1 <= pj) ? 64 * (s + 1) : 64 * (s - pj);
#pragma unroll
      for (int i = 0; i < 4; i++) {
        const int row = i * 16 + (tid >> 4);
        __builtin_amdgcn_global_load_lds(
            (const AS1 void*)(kbase + (long)(kvn + row) * 128 + scol * 8),
            (AS3 void*)(&Kb[cur ^ 1][(i * 256 + tid) * 8]), 16, 0, 0);
      }
    }
    __builtin_amdgcn_sched_barrier(0);

    // 3. QK^T from LDS K tile
    f32x4_t sc[4];
#pragma unroll
    for (int t = 0; t < 4; t++) sc[t] = (f32x4_t){0.f, 0.f, 0.f, 0.f};
    const unsigned short* Kcur = &Kb[cur][0];
    __builtin_amdgcn_s_setprio(1);
#pragma unroll
    for (int t = 0; t < 4; t++) {
      const unsigned short* krow = Kcur + (16 * t + r) * 128;
#pragma unroll
      for (int c = 0; c < 4; c++) {
        const bf16x8_t kf = *(const bf16x8_t*)(krow + (((4 * c + g) ^ rs) << 3));
        sc[t] = __builtin_amdgcn_mfma_f32_16x16x32_bf16(kf, qf[c], sc[t], 0, 0, 0);
      }
    }
    __builtin_amdgcn_s_setprio(0);

    // 4. causal mask on the current tile's last stage
    if (s == pj || s == 32) {
#pragma unroll
      for (int t = 0; t < 4; t++)
#pragma unroll
        for (int jj = 0; jj < 4; jj++)
          if (t * 16 + 4 * g + jj > wid * 16 + r) sc[t][jj] = -1e30f;
    }
    // 5. softmax (defer-max fast path)
    float lm = sc[0][0];
#pragma unroll
    for (int t = 0; t < 4; t++)
#pragma unroll
      for (int jj = 0; jj < 4; jj++) lm = fmaxf(lm, sc[t][jj]);
    if (!__all(lm <= m + 8.f)) {  // rare rescale path
      float pm = lm;
      pm = fmaxf(pm, __shfl_xor(pm, 16));
      pm = fmaxf(pm, __shfl_xor(pm, 32));
      const float mnew = fmaxf(m, pm);
      const float alpha = __expf(m - mnew);
      lsum *= alpha;
      float aj[4];
#pragma unroll
      for (int jj = 0; jj < 4; jj++) aj[jj] = __shfl(alpha, 4 * g + jj);
#pragma unroll
      for (int dt = 0; dt < 8; dt++) {
        o[dt][0] *= aj[0]; o[dt][1] *= aj[1]; o[dt][2] *= aj[2]; o[dt][3] *= aj[3];
      }
      m = mnew;
    }
    float p[16];
#pragma unroll
    for (int t = 0; t < 4; t++)
#pragma unroll
      for (int jj = 0; jj < 4; jj++) p[4 * t + jj] = __expf(sc[t][jj] - m);
    float ls = 0.f;
#pragma unroll
    for (int i = 0; i < 16; i++) ls += p[i];
    lsum += ls;

    // 6. P redistribute through per-wave LDS tile
    asm volatile("" ::: "memory");
#pragma unroll
    for (int t = 0; t < 4; t++) {
      uint2 w = {pack2bf(p[4 * t], p[4 * t + 1]), pack2bf(p[4 * t + 2], p[4 * t + 3])};
      *(uint2*)(pw + r * 128 + (((2 * t + (g >> 1)) ^ rs) << 4) + ((g & 1) << 3)) = w;
    }
    asm volatile("s_waitcnt lgkmcnt(0)" ::: "memory");
    const bf16x8_t pa0 = *(const bf16x8_t*)(pw + r * 128 + ((g ^ rs) << 4));
    const bf16x8_t pa1 = *(const bf16x8_t*)(pw + r * 128 + (((4 + g) ^ rs) << 4));

    // 7. V visibility: own V-DMAs done (K-next still in flight), then barrier
    if (s < 32)
      asm volatile("s_waitcnt vmcnt(4)" ::: "memory");
    else
      asm volatile("s_waitcnt vmcnt(0)" ::: "memory");
    __builtin_amdgcn_s_barrier();

    // 8. PV from LDS V tile (swizzled ds_read_b128)
    __builtin_amdgcn_s_setprio(1);
#pragma unroll
    for (int dt = 0; dt < 8; dt++) {
      const bf16x8_t vfA = *(const bf16x8_t*)(Vb + (dt * 16 + r) * 64 + ((g ^ rs) << 3));
      o[dt] = __builtin_amdgcn_mfma_f32_16x16x32_bf16(pa0, vfA, o[dt], 0, 0, 0);
    }
#pragma unroll
    for (int dt = 0; dt < 8; dt++) {
      const bf16x8_t vfB = *(const bf16x8_t*)(Vb + (dt * 16 + r) * 64 + (((4 + g) ^ rs) << 3));
      o[dt] = __builtin_amdgcn_mfma_f32_16x16x32_bf16(pa1, vfB, o[dt], 0, 0, 0);
    }
    __builtin_amdgcn_s_setprio(0);

    // 9. drain K(s+1) staging + sync (protects Vb/Kb for next stage)
    asm volatile("s_waitcnt vmcnt(0)" ::: "memory");
    __builtin_amdgcn_s_barrier();
  }
  // epilogue: flush tile B
  {
    float lt = lsum;
    lt += __shfl_xor(lt, 16);
    lt += __shfl_xor(lt, 32);
    float rl[4];
#pragma unroll
    for (int jj = 0; jj < 4; jj++) rl[jj] = 1.0f / __shfl(lt, 4 * g + jj);
    unsigned short* aop = ao + ((long)(b * 2048 + tile * 64 + wid * 16 + 4 * g)) * 2048 + h * 128 + r;
#pragma unroll
    for (int dt = 0; dt < 8; dt++)
#pragma unroll
      for (int jj = 0; jj < 4; jj++)
        aop[(long)jj * 2048 + dt * 16] = f2bf(o[dt][jj] * rl[jj]);
  }
}

extern "C" void kernel_launch(void* const* d_in, const int* in_sizes, int n_in,
                              void* d_out, int out_size, void* d_ws, size_t ws_size,
                              hipStream_t stream) {
  const float* x    = (const float*)d_in[0];
  const float* sinp = (const float*)d_in[1];
  const float* cosp = (const float*)d_in[2];
  const float* Wqkv = (const float*)d_in[3];
  const float* Wo   = (const float*)d_in[4];
  float* out = (float*)d_out;
  char* ws = (char*)d_ws;

  const int B = 2, T = 2048, D = 2048, H = 16, HD = 128;
  const int M = B * T;        // 4096
  const int NQ = D + 2 * HD;  // 2304

  unsigned short* xb    = (unsigned short*)(ws + 0);         // 16,777,216
  unsigned short* wqkvT = (unsigned short*)(ws + 16777216);  //  9,437,184
  unsigned short* woT   = (unsigned short*)(ws + 26214400);  //  8,388,608
  float*          qkv   = (float*)         (ws + 34603008);  // 37,748,736
  unsigned short* qr    = (unsigned short*)(ws + 72351744);  // 16,777,216
  unsigned short* kr    = (unsigned short*)(ws + 89128960);  //  1,048,576
  unsigned short* vT    = (unsigned short*)(ws + 90177536);  //  1,048,576
  unsigned short* ao    = xb;  // reuse xb after first GEMM

  dim3 tb(64, 4);
  cvt_bf16_kernel<<<(M * D) / 1024, 256, 0, stream>>>(x, xb);
  transpose_f32_bf16<<<dim3(NQ / 64, D / 64, 1), tb, 0, stream>>>(Wqkv, wqkvT, NQ, D, 0, 0);
  transpose_f32_bf16<<<dim3(D / 64, D / 64, 1), tb, 0, stream>>>(Wo, woT, D, D, 0, 0);
  gemm_bt<<<dim3((NQ / 128) * (M / 128)), 256, 0, stream>>>(xb, wqkvT, qkv, M, NQ, D, NQ / 128);
  rope_kernel<<<M, 256, 0, stream>>>(qkv, sinp, cosp, qr, kr);
  transpose_f32_bf16<<<dim3(HD / 64, T / 64, B), tb, 0, stream>>>(
      qkv + 2176, vT, NQ, T, (long)T * NQ, (long)HD * T);
  mqa_attn<<<dim3(512), 256, 0, stream>>>(qr, kr, vT, ao);
  gemm_bt<<<dim3((D / 128) * (M / 128)), 256, 0, stream>>>(ao, woT, out, M, D, D, D / 128);
}